// Round 6
// baseline (385.962 us; speedup 1.0000x reference)
//
#include <hip/hip_runtime.h>
#include <stdint.h>

#define BN_EPS 1e-3f

constexpr int Bn = 32, H = 56, W = 56, C = 256;
constexpr int WPC = 8;            // u32 words per 256-channel bit vector
constexpr int HO = 28, WO = 28;   // pooled output dims
constexpr int NW = 72;            // 9 taps * 8 words

// ---------------------------------------------------------------------------
// Binarize x: bit c = (x >= 0). Pack via wave ballot.
__global__ __launch_bounds__(256) void k_binarize_x(const float* __restrict__ x,
                                                    uint32_t* __restrict__ xbits) {
  int i = blockIdx.x * 256 + threadIdx.x;
  float v = x[i];
  unsigned long long m = __ballot(v >= 0.0f);
  if ((threadIdx.x & 63) == 0) {
    ((unsigned long long*)xbits)[i >> 6] = m;
  }
}

// ---------------------------------------------------------------------------
// Binarize weights HWIO [3][3][256 ic][256 oc] -> wbT[oc][j], j = tap*8+word.
__global__ __launch_bounds__(256) void k_binarize_w(const float* __restrict__ w,
                                                    uint32_t* __restrict__ wbT) {
  int j = blockIdx.x;        // 0..71
  int oc = threadIdx.x;      // 0..255
  int tap = j >> 3, ww = j & 7;
  const float* base = w + ((size_t)(tap * C) + ww * 32) * C + oc;
  uint32_t bits = 0;
#pragma unroll
  for (int b = 0; b < 32; ++b) {
    float v = base[(size_t)b * C];
    bits |= (v >= 0.0f ? 1u : 0u) << b;
  }
  wbT[(size_t)oc * NW + j] = bits;
}

// ---------------------------------------------------------------------------
__device__ __forceinline__ void corr3(const int* pw, bool rv0, bool rv2,
                                      int& cI, int& cL, int& cR) {
  int nvI = 0, pvI = 0, nvL = 0, pvL = 0, nvR = 0, pvR = 0;
#pragma unroll
  for (int ky = 0; ky < 3; ++ky) {
    bool rvk = (ky == 0) ? rv0 : ((ky == 2) ? rv2 : true);
#pragma unroll
    for (int kx = 0; kx < 3; ++kx) {
      int p = pw[ky * 3 + kx];
      if (rvk) nvI++; else pvI += p;
      if (rvk && kx != 0) nvL++; else pvL += p;
      if (rvk && kx != 2) nvR++; else pvR += p;
    }
  }
  cI = 256 * nvI + 2 * pvI;
  cL = 256 * nvL + 2 * pvL;
  cR = 256 * nvR + 2 * pvR;
}

// ct1[oc][0..8]: conv1 integer thresholds T = (corr - ceil(t1)) >> 1 for row
// cases {int, top, bot} x col {I,L,R}; [9] = sub0 (popc of all kx=0 weights).
// ct2[oc][0..8]: conv2 raw corr values, same order; [9] = sub0.
__global__ __launch_bounds__(256) void k_prep(
    const uint32_t* __restrict__ wb1, const uint32_t* __restrict__ wb2,
    const float* __restrict__ beta1, const float* __restrict__ mean1,
    const float* __restrict__ var1, const float* __restrict__ beta2,
    const float* __restrict__ mean2, const float* __restrict__ var2,
    int* __restrict__ ct1, int* __restrict__ ct2,
    float* __restrict__ a2t, float* __restrict__ b2t) {
  int oc = threadIdx.x;
  {
    int* ct = ct1 + oc * 10;
    int pw[9];
#pragma unroll
    for (int t = 0; t < 9; ++t) {
      int acc = 0;
#pragma unroll
      for (int w = 0; w < 8; ++w) acc += __popc(wb1[(size_t)oc * NW + t * 8 + w]);
      pw[t] = acc;
    }
    float t1 = mean1[oc] - beta1[oc] * sqrtf(var1[oc] + BN_EPS);
    int it1 = (int)ceilf(t1);
    int c[9];
    corr3(pw, true, true, c[0], c[1], c[2]);
    corr3(pw, false, true, c[3], c[4], c[5]);
    corr3(pw, true, false, c[6], c[7], c[8]);
#pragma unroll
    for (int k = 0; k < 9; ++k) ct[k] = (c[k] - it1) >> 1;
    ct[9] = pw[0] + pw[3] + pw[6];
  }
  {
    int* ct = ct2 + oc * 10;
    int pw[9];
#pragma unroll
    for (int t = 0; t < 9; ++t) {
      int acc = 0;
#pragma unroll
      for (int w = 0; w < 8; ++w) acc += __popc(wb2[(size_t)oc * NW + t * 8 + w]);
      pw[t] = acc;
    }
    corr3(pw, true, true, ct[0], ct[1], ct[2]);
    corr3(pw, false, true, ct[3], ct[4], ct[5]);
    corr3(pw, true, false, ct[6], ct[7], ct[8]);
    ct[9] = pw[0] + pw[3] + pw[6];
  }
  float s2 = rsqrtf(var2[oc] + BN_EPS);
  a2t[oc] = s2;
  b2t[oc] = beta2[oc] - mean2[oc] * s2;
}

// ---------------------------------------------------------------------------
// Named-scalar input tile: 4 rows x 8 words, NO arrays (rule #20: runtime-
// indexed allocas go to scratch; SROA runs before unroll). Everything below
// is macro-unrolled with literal indices so all 32 words live in VGPRs.

#define DECL_ROW(i) \
  uint32_t x##i##0, x##i##1, x##i##2, x##i##3, x##i##4, x##i##5, x##i##6, x##i##7

#define LOAD_ROW(i, bits, b, rr, c)                                         \
  do {                                                                      \
    if ((unsigned)(rr) < (unsigned)H && (c) < W) {                          \
      const uint32_t* p_ = (bits) + (((size_t)(b)*H + (rr)) * W + (c)) * WPC; \
      uint4 a_ = *(const uint4*)p_;                                         \
      uint4 d_ = *(const uint4*)(p_ + 4);                                   \
      x##i##0 = a_.x; x##i##1 = a_.y; x##i##2 = a_.z; x##i##3 = a_.w;       \
      x##i##4 = d_.x; x##i##5 = d_.y; x##i##6 = d_.z; x##i##7 = d_.w;       \
    } else {                                                                \
      x##i##0 = x##i##1 = x##i##2 = x##i##3 = 0u;                           \
      x##i##4 = x##i##5 = x##i##6 = x##i##7 = 0u;                           \
    }                                                                       \
  } while (0)

// One (ky,w) tap against 3 kx weight slices for rows A and B.
#define XOP(xa, xb, kb, w)                                                  \
  do {                                                                      \
    const uint32_t w0_ = wp[(kb) + (w)];                                    \
    const uint32_t w1_ = wp[(kb) + 8 + (w)];                                \
    const uint32_t w2_ = wp[(kb) + 16 + (w)];                               \
    q0A += __popc((xa) ^ w0_); q1A += __popc((xa) ^ w1_);                   \
    q2A += __popc((xa) ^ w2_);                                              \
    q0B += __popc((xb) ^ w0_); q1B += __popc((xb) ^ w1_);                   \
    q2B += __popc((xb) ^ w2_);                                              \
  } while (0)

#define ROW8(ra, rb, kb)                                                    \
  XOP(x##ra##0, x##rb##0, kb, 0); XOP(x##ra##1, x##rb##1, kb, 1);           \
  XOP(x##ra##2, x##rb##2, kb, 2); XOP(x##ra##3, x##rb##3, kb, 3);           \
  XOP(x##ra##4, x##rb##4, kb, 4); XOP(x##ra##5, x##rb##5, kb, 5);           \
  XOP(x##ra##6, x##rb##6, kb, 6); XOP(x##ra##7, x##rb##7, kb, 7)

// Full 3x3x256 core for output rows A (x0..x2) and B (x1..x3).
#define CORE()                                                              \
  uint32_t q0A = 0, q1A = 0, q2A = 0, q0B = 0, q1B = 0, q2B = 0;            \
  ROW8(0, 1, 0);                                                            \
  ROW8(1, 2, 24);                                                           \
  ROW8(2, 3, 48)

// Neighbor-combine with rows packed into 16-bit halves (max sum 2304 <
// 2^16, carry-free). Produces PA, PB.
#define COMBINE(sub0)                                                       \
  uint32_t pk0_ = q0A | (q0B << 16);                                        \
  uint32_t pk2_ = q2A | (q2B << 16);                                        \
  uint32_t u0_ = (uint32_t)__shfl_up((int)pk0_, 1);                         \
  uint32_t d2_ = (uint32_t)__shfl_down((int)pk2_, 1);                       \
  if (lane == 0) u0_ = (uint32_t)(sub0) * 0x10001u;                         \
  uint32_t Pp_ = u0_ + (q1A | (q1B << 16)) + d2_;                           \
  const int PA = (int)(Pp_ & 0xffffu), PB = (int)(Pp_ >> 16)

// ---------------------------------------------------------------------------
// Conv1 (XNOR) + BN1 + sign -> packed bits. Wave = row pair, 32 oc.
__global__ __launch_bounds__(256, 2) void k_conv1(
    const uint32_t* __restrict__ xbits, const uint32_t* __restrict__ wbT,
    const int* __restrict__ ctab, uint32_t* __restrict__ hbits) {
  const int lane = threadIdx.x & 63;
  const int q = __builtin_amdgcn_readfirstlane(blockIdx.x * 4 + (threadIdx.x >> 6));
  const int b = blockIdx.y;
  const int z = blockIdx.z;
  const int ocbase = z * 32;
  const int rA = 2 * q;
  const int c = lane;
  const bool top = (q == 0), bot = (q == 27);

  DECL_ROW(0); DECL_ROW(1); DECL_ROW(2); DECL_ROW(3);
  LOAD_ROW(0, xbits, b, rA - 1, c);
  LOAD_ROW(1, xbits, b, rA, c);
  LOAD_ROW(2, xbits, b, rA + 1, c);
  LOAD_ROW(3, xbits, b, rA + 2, c);

  uint32_t bitsA = 0, bitsB = 0;

  for (int ocl = 0; ocl < 32; ++ocl) {
    const uint32_t* wp = wbT + (size_t)(ocbase + ocl) * NW;
    const int* ct = ctab + (ocbase + ocl) * 10;
    const int* ctA = ct + (top ? 3 : 0);
    const int* ctB = ct + (bot ? 6 : 0);

    CORE();
    COMBINE(ct[9]);

    const int TA = (lane == 0) ? ctA[1] : ((lane == W - 1) ? ctA[2] : ctA[0]);
    const int TB = (lane == 0) ? ctB[1] : ((lane == W - 1) ? ctB[2] : ctB[0]);
    bitsA |= (uint32_t)((PA <= TA) ? 1u : 0u) << ocl;
    bitsB |= (uint32_t)((PB <= TB) ? 1u : 0u) << ocl;
  }

  if (c < W) {
    size_t base = (((size_t)b * H + rA) * W + c) * WPC + z;
    hbits[base] = bitsA;
    hbits[base + W * WPC] = bitsB;
  }
}

// ---------------------------------------------------------------------------
// Conv2 (XNOR) + 2x2 maxpool + BN2 -> f32. Wave = one pooled row, 32 oc.
__global__ __launch_bounds__(256, 2) void k_conv2(
    const uint32_t* __restrict__ hbits, const uint32_t* __restrict__ wbT,
    const int* __restrict__ ctab, const float* __restrict__ a2t,
    const float* __restrict__ b2t, float* __restrict__ out) {
  const int lane = threadIdx.x & 63;
  const int ro = __builtin_amdgcn_readfirstlane(blockIdx.x * 4 + (threadIdx.x >> 6));
  const int b = blockIdx.y;
  const int z = blockIdx.z;
  const int ocbase = z * 32;
  const int rA = 2 * ro;
  const int c = lane;
  const bool top = (ro == 0), bot = (ro == 27);

  DECL_ROW(0); DECL_ROW(1); DECL_ROW(2); DECL_ROW(3);
  LOAD_ROW(0, hbits, b, rA - 1, c);
  LOAD_ROW(1, hbits, b, rA, c);
  LOAD_ROW(2, hbits, b, rA + 1, c);
  LOAD_ROW(3, hbits, b, rA + 2, c);

  const bool writer = ((lane & 1) == 0) && (lane < W);
  float* orow = out + (((size_t)b * HO + ro) * WO + (lane >> 1)) * C + ocbase;

#define OCSTEP(tout, ocl)                                                   \
  {                                                                         \
    const uint32_t* wp = wbT + (size_t)(ocbase + (ocl)) * NW;               \
    const int* ct = ctab + (ocbase + (ocl)) * 10;                           \
    const int* cA = ct + (top ? 3 : 0);                                     \
    const int* cB = ct + (bot ? 6 : 0);                                     \
    CORE();                                                                 \
    COMBINE(ct[9]);                                                         \
    const int corrA = (lane == 0) ? cA[1] : ((lane == W - 1) ? cA[2] : cA[0]); \
    const int corrB = (lane == 0) ? cB[1] : ((lane == W - 1) ? cB[2] : cB[0]); \
    tout = max(corrA - 2 * PA, corrB - 2 * PB);                             \
  }

  for (int g = 0; g < 8; ++g) {
    const int oc0 = g * 4;
    int t0, t1, t2, t3;
    OCSTEP(t0, oc0 + 0)
    OCSTEP(t1, oc0 + 1)
    OCSTEP(t2, oc0 + 2)
    OCSTEP(t3, oc0 + 3)
    int x0 = __shfl_xor(t0, 1), x1 = __shfl_xor(t1, 1);
    int x2 = __shfl_xor(t2, 1), x3 = __shfl_xor(t3, 1);
    if (writer) {
      const int oa = ocbase + oc0;
      float o0 = (float)max(t0, x0) * a2t[oa + 0] + b2t[oa + 0];
      float o1 = (float)max(t1, x1) * a2t[oa + 1] + b2t[oa + 1];
      float o2 = (float)max(t2, x2) * a2t[oa + 2] + b2t[oa + 2];
      float o3 = (float)max(t3, x3) * a2t[oa + 3] + b2t[oa + 3];
      *(float4*)(orow + oc0) = make_float4(o0, o1, o2, o3);
    }
  }
#undef OCSTEP
}

// ---------------------------------------------------------------------------
extern "C" void kernel_launch(void* const* d_in, const int* in_sizes, int n_in,
                              void* d_out, int out_size, void* d_ws, size_t ws_size,
                              hipStream_t stream) {
  const float* x     = (const float*)d_in[0];
  const float* w1    = (const float*)d_in[1];
  const float* beta1 = (const float*)d_in[2];
  const float* mean1 = (const float*)d_in[3];
  const float* var1  = (const float*)d_in[4];
  const float* w2    = (const float*)d_in[5];
  const float* beta2 = (const float*)d_in[6];
  const float* mean2 = (const float*)d_in[7];
  const float* var2  = (const float*)d_in[8];
  float* out = (float*)d_out;

  uint32_t* ws32 = (uint32_t*)d_ws;
  const size_t XBW = (size_t)Bn * H * W * WPC;  // 802816 u32
  uint32_t* xbits = ws32;
  uint32_t* hbits = xbits + XBW;
  uint32_t* wb1   = hbits + XBW;
  uint32_t* wb2   = wb1 + (size_t)C * NW;
  int* ct1        = (int*)(wb2 + (size_t)C * NW);
  int* ct2        = ct1 + C * 10;
  float* a2t      = (float*)(ct2 + C * 10);
  float* b2t      = a2t + C;

  k_binarize_x<<<dim3((Bn * H * W * C) / 256), 256, 0, stream>>>(x, xbits);
  k_binarize_w<<<dim3(NW), 256, 0, stream>>>(w1, wb1);
  k_binarize_w<<<dim3(NW), 256, 0, stream>>>(w2, wb2);
  k_prep<<<dim3(1), 256, 0, stream>>>(wb1, wb2, beta1, mean1, var1,
                                      beta2, mean2, var2, ct1, ct2, a2t, b2t);
  k_conv1<<<dim3(7, Bn, 8), 256, 0, stream>>>(xbits, wb1, ct1, hbits);
  k_conv2<<<dim3(7, Bn, 8), 256, 0, stream>>>(hbits, wb2, ct2, a2t, b2t, out);
}

// Round 7
// 224.004 us; speedup vs baseline: 1.7230x; 1.7230x over previous
//
#include <hip/hip_runtime.h>
#include <stdint.h>

#define BN_EPS 1e-3f

constexpr int Bn = 32, H = 56, Wd = 56, C = 256;
constexpr int HO = 28, WO = 28;
constexpr int NSTEP = 36;          // K = 2304 = 36 * 64
constexpr int MT = 112;            // pixels per block = 2 image rows
constexpr int APAD = 80;           // LDS row stride for A (64B data + pad)
constexpr int BPAD = 80;           // LDS row stride for B^T
constexpr int ASZ = MT * APAD;     // 8960
constexpr int BSZ = 256 * BPAD;    // 20480

typedef int v4i __attribute__((ext_vector_type(4)));

__device__ __forceinline__ int imax(int a, int b) { return a > b ? a : b; }

// ---------------------------------------------------------------------------
// sign(x) -> i8 {+1,-1}, 4 elems/thread.
__global__ __launch_bounds__(256) void k_sign_x(const float* __restrict__ x,
                                                int8_t* __restrict__ xs, int n4) {
  int i = blockIdx.x * 256 + threadIdx.x;
  if (i >= n4) return;
  float4 v = ((const float4*)x)[i];
  char4 s;
  s.x = v.x >= 0.f ? 1 : -1;
  s.y = v.y >= 0.f ? 1 : -1;
  s.z = v.z >= 0.f ? 1 : -1;
  s.w = v.w >= 0.f ? 1 : -1;
  ((char4*)xs)[i] = s;
}

// ---------------------------------------------------------------------------
// Weights HWIO [9 tap][256 ic][256 oc] f32 -> wT[tap][oc][ic] i8 (sign).
// Thread = one u32 (4 ic bytes) of the output; output writes coalesced.
__global__ __launch_bounds__(256) void k_sign_wT(const float* __restrict__ w,
                                                 int8_t* __restrict__ wt) {
  int u = blockIdx.x * 256 + threadIdx.x;       // 0 .. 147456
  int tap = u >> 14;
  int rem = u & 16383;
  int oc = rem >> 6;
  int icq = rem & 63;                           // ic block of 4
  uint32_t pk = 0;
#pragma unroll
  for (int j = 0; j < 4; ++j) {
    float v = w[((size_t)(tap * 256 + icq * 4 + j)) * 256 + oc];
    uint32_t b = (v >= 0.f) ? 0x01u : 0xFFu;    // +1 / -1 as i8
    pk |= b << (8 * j);
  }
  ((uint32_t*)wt)[u] = pk;
}

// ---------------------------------------------------------------------------
// Implicit-GEMM conv, 3x3 SAME, M-tile=112 (2 rows of one image), N=256.
// MODE 0: +BN1 threshold -> i8 sign output (hs)
// MODE 1: +2x2 maxpool +BN2 -> f32 output
template <int MODE>
__global__ __launch_bounds__(256, 2) void k_conv(
    const int8_t* __restrict__ src,   // xs or hs, NHWC i8
    const int8_t* __restrict__ wT,    // [9][256 oc][256 ic] i8
    const float* __restrict__ beta, const float* __restrict__ mean,
    const float* __restrict__ var,
    int8_t* __restrict__ hs,          // MODE 0
    float* __restrict__ outp)         // MODE 1
{
  const int t = threadIdx.x;
  const int lane = t & 63;
  const int wv = t >> 6;            // wave 0..3 -> oc quarter
  const int rp = blockIdx.x;        // row pair 0..27
  const int b = blockIdx.y;
  const int rr0 = rp * 2;
  const int m0 = (b * 28 + rp) * MT;
  const int grp = lane >> 4, lid = lane & 15;
  const int wbase = wv * 64;

  __shared__ __align__(16) int8_t lds[2 * (ASZ + BSZ)];
  int8_t* const A0 = lds;
  int8_t* const B0 = lds + ASZ;
  int8_t* const A1 = lds + ASZ + BSZ;
  int8_t* const B1 = lds + 2 * ASZ + BSZ;

  // --- staging helpers (issue loads to regs; write regs to LDS later) ---
  uint4 av0, av1, bv0, bv1, bv2, bv3;
  auto stage_issue = [&](int s) {
    const int tap = s >> 2, icoff = (s & 3) << 6;
    const int ky = tap / 3, kx = tap % 3;
    // B^T tile: row oc = t, 64 bytes of ic
    {
      const uint4* q = (const uint4*)(wT + (((size_t)tap * 256 + t) << 8) + icoff);
      bv0 = q[0]; bv1 = q[1]; bv2 = q[2]; bv3 = q[3];
    }
    // A tile: 112 rows x 64B, 2 threads per row
    if (t < 224) {
      const int lm = t >> 1, half = t & 1;
      const int rflag = lm >= 56;
      const int cc = lm - (rflag ? 56 : 0);
      const int sr = rr0 + rflag + ky - 1;
      const int sc = cc + kx - 1;
      if ((unsigned)sr < 56u && (unsigned)sc < 56u) {
        const uint4* q = (const uint4*)(src + (((size_t)(b * 56 + sr) * 56 + sc) << 8)
                                        + icoff + (half << 5));
        av0 = q[0]; av1 = q[1];
      } else {
        uint4 z; z.x = z.y = z.z = z.w = 0u;
        av0 = z; av1 = z;
      }
    }
  };
  auto stage_write = [&](int8_t* Ab, int8_t* Bb) {
    {
      uint4* d = (uint4*)(Bb + t * BPAD);
      d[0] = bv0; d[1] = bv1; d[2] = bv2; d[3] = bv3;
    }
    if (t < 224) {
      const int lm = t >> 1, half = t & 1;
      uint4* d = (uint4*)(Ab + lm * APAD + (half << 5));
      d[0] = av0; d[1] = av1;
    }
  };

  v4i acc[7][4];
#pragma unroll
  for (int i = 0; i < 7; ++i)
#pragma unroll
    for (int j = 0; j < 4; ++j) acc[i][j] = (v4i){0, 0, 0, 0};

  stage_issue(0);
  stage_write(A0, B0);
  __syncthreads();

  int cur = 0;
  for (int s = 0; s < NSTEP; ++s) {
    int8_t* const Ac = cur ? A1 : A0;
    int8_t* const Bc = cur ? B1 : B0;
    const bool more = (s + 1 < NSTEP);
    if (more) stage_issue(s + 1);

    v4i af[7], bf[4];
#pragma unroll
    for (int ms = 0; ms < 7; ++ms)
      af[ms] = *(const v4i*)(Ac + (ms * 16 + lid) * APAD + grp * 16);
#pragma unroll
    for (int ns = 0; ns < 4; ++ns)
      bf[ns] = *(const v4i*)(Bc + (wbase + ns * 16 + lid) * BPAD + grp * 16);
#pragma unroll
    for (int ms = 0; ms < 7; ++ms)
#pragma unroll
      for (int ns = 0; ns < 4; ++ns)
        acc[ms][ns] = __builtin_amdgcn_mfma_i32_16x16x64_i8(af[ms], bf[ns],
                                                            acc[ms][ns], 0, 0, 0);
    if (more) stage_write(cur ? A0 : A1, cur ? B0 : B1);
    __syncthreads();
    cur ^= 1;
  }

  // --- epilogue ---
  if (MODE == 0) {
    // BN1 + sign -> i8
#pragma unroll
    for (int ns = 0; ns < 4; ++ns) {
      const int oc = wbase + ns * 16 + lid;
      const float mu = mean[oc], rs = rsqrtf(var[oc] + BN_EPS), be = beta[oc];
#pragma unroll
      for (int ms = 0; ms < 7; ++ms)
#pragma unroll
        for (int q = 0; q < 4; ++q) {
          float bnv = ((float)acc[ms][ns][q] - mu) * rs + be;
          hs[(size_t)(m0 + ms * 16 + grp * 4 + q) * 256 + oc] =
              bnv >= 0.f ? (int8_t)1 : (int8_t)-1;
        }
    }
  } else {
    // 2x2 maxpool + BN2 -> f32
#pragma unroll
    for (int ns = 0; ns < 4; ++ns) {
      const int oc = wbase + ns * 16 + lid;
      const float mu = mean[oc], rs = rsqrtf(var[oc] + BN_EPS), be = beta[oc];
      int hm[7][2], sx[7][2];
#pragma unroll
      for (int ms = 0; ms < 7; ++ms) {
        hm[ms][0] = imax(acc[ms][ns][0], acc[ms][ns][1]);
        hm[ms][1] = imax(acc[ms][ns][2], acc[ms][ns][3]);
      }
#pragma unroll
      for (int ms = 3; ms < 7; ++ms) {
        sx[ms][0] = __shfl_xor(hm[ms][0], 32);
        sx[ms][1] = __shfl_xor(hm[ms][1], 32);
      }
      float* const obase = outp + ((size_t)(b * 28 + rp) * 28) * 256 + oc;
#pragma unroll
      for (int ms = 0; ms < 4; ++ms)
#pragma unroll
        for (int q2 = 0; q2 < 2; ++q2) {
          int part; bool top;
          if (ms < 3) {  // static branch
            top = true;
            part = (grp < 2) ? sx[ms + 3][q2] : sx[ms + 4][q2];
          } else {
            top = (grp < 2);
            part = sx[6][q2];
          }
          if (top) {
            const int m = ms * 16 + grp * 4 + 2 * q2;  // even, < 56
            const int mx = imax(hm[ms][q2], part);
            obase[(size_t)(m >> 1) * 256] = ((float)mx - mu) * rs + be;
          }
        }
    }
  }
}

// ---------------------------------------------------------------------------
extern "C" void kernel_launch(void* const* d_in, const int* in_sizes, int n_in,
                              void* d_out, int out_size, void* d_ws, size_t ws_size,
                              hipStream_t stream) {
  const float* x     = (const float*)d_in[0];
  const float* w1    = (const float*)d_in[1];
  const float* beta1 = (const float*)d_in[2];
  const float* mean1 = (const float*)d_in[3];
  const float* var1  = (const float*)d_in[4];
  const float* w2    = (const float*)d_in[5];
  const float* beta2 = (const float*)d_in[6];
  const float* mean2 = (const float*)d_in[7];
  const float* var2  = (const float*)d_in[8];
  float* out = (float*)d_out;

  const size_t NPIX = (size_t)Bn * H * Wd * C;  // 25690112
  int8_t* xs  = (int8_t*)d_ws;
  int8_t* hs  = xs + NPIX;
  int8_t* w1t = hs + NPIX;
  int8_t* w2t = w1t + 9 * 256 * 256;

  k_sign_x<<<dim3((int)(NPIX / 4 / 256)), 256, 0, stream>>>(x, xs, (int)(NPIX / 4));
  k_sign_wT<<<dim3(576), 256, 0, stream>>>(w1, w1t);
  k_sign_wT<<<dim3(576), 256, 0, stream>>>(w2, w2t);
  k_conv<0><<<dim3(28, Bn), 256, 0, stream>>>(xs, w1t, beta1, mean1, var1, hs, nullptr);
  k_conv<1><<<dim3(28, Bn), 256, 0, stream>>>(hs, w2t, beta2, mean2, var2, nullptr, out);
}

// Round 8
// 198.256 us; speedup vs baseline: 1.9468x; 1.1299x over previous
//
#include <hip/hip_runtime.h>
#include <stdint.h>

#define BN_EPS 1e-3f

constexpr int Bn = 32, H = 56, Wd = 56, C = 256;
constexpr int HO = 28, WO = 28;
constexpr int NSTEP = 36;            // K = 2304 = 36 * 64
constexpr int MT = 112;              // pixels per block = 2 image rows
constexpr int ACOLS = 58;            // 56 + 2 halo cols
constexpr int ASTRIDE = 272;         // bytes per (row,col) slot: 256B data + 16B pad

typedef int v4i __attribute__((ext_vector_type(4)));

__device__ __forceinline__ int imax(int a, int b) { return a > b ? a : b; }

// ---------------------------------------------------------------------------
// sign(x) -> i8 {+1,-1}, 4 elems/thread.
__global__ __launch_bounds__(256) void k_sign_x(const float* __restrict__ x,
                                                int8_t* __restrict__ xs, int n4) {
  int i = blockIdx.x * 256 + threadIdx.x;
  if (i >= n4) return;
  float4 v = ((const float4*)x)[i];
  char4 s;
  s.x = v.x >= 0.f ? 1 : -1;
  s.y = v.y >= 0.f ? 1 : -1;
  s.z = v.z >= 0.f ? 1 : -1;
  s.w = v.w >= 0.f ? 1 : -1;
  ((char4*)xs)[i] = s;
}

// ---------------------------------------------------------------------------
// Weights HWIO [9 tap][256 ic][256 oc] f32 -> wT[tap][oc][ic] i8 (sign).
__global__ __launch_bounds__(256) void k_sign_wT(const float* __restrict__ w,
                                                 int8_t* __restrict__ wt) {
  int u = blockIdx.x * 256 + threadIdx.x;       // 0 .. 147455
  int tap = u >> 14;
  int rem = u & 16383;
  int oc = rem >> 6;
  int icq = rem & 63;                           // ic block of 4
  uint32_t pk = 0;
#pragma unroll
  for (int j = 0; j < 4; ++j) {
    float v = w[((size_t)(tap * 256 + icq * 4 + j)) * 256 + oc];
    uint32_t b = (v >= 0.f) ? 0x01u : 0xFFu;    // +1 / -1 as i8
    pk |= b << (8 * j);
  }
  ((uint32_t*)wt)[u] = pk;
}

// ---------------------------------------------------------------------------
// Implicit-GEMM conv, 3x3 SAME. A (4 src rows + halo) staged in LDS ONCE;
// K-loop has no barriers: 7 tap-shifted ds_reads (imm offsets) + 4 direct
// global B-fragment loads (L2-hot, reg double-buffered) + 28 MFMA per step.
// MODE 0: +BN1 threshold -> i8 sign output; MODE 1: +2x2 maxpool +BN2 -> f32.
template <int MODE>
__global__ __launch_bounds__(256, 2) void k_conv(
    const int8_t* __restrict__ src,   // xs or hs, NHWC i8
    const int8_t* __restrict__ wT,    // [9][256 oc][256 ic] i8
    const float* __restrict__ beta, const float* __restrict__ mean,
    const float* __restrict__ var,
    int8_t* __restrict__ hs,          // MODE 0
    float* __restrict__ outp)         // MODE 1
{
  const int t = threadIdx.x;
  const int lane = t & 63;
  const int wv = t >> 6;              // wave 0..3 -> oc quarter
  const int rp = blockIdx.x;          // row pair 0..27
  const int b = blockIdx.y;
  const int rr0 = rp * 2;
  const int m0 = (b * 28 + rp) * MT;
  const int grp = lane >> 4, lid = lane & 15;
  const int wbase = wv * 64;

  __shared__ __align__(16) int8_t As[4 * ACOLS * ASTRIDE];  // 63104 B

  // ---- stage A once: 4 src rows (rr0-1 .. rr0+2) x 58 cols (halo), zeros OOB
  for (int idx = t; idx < 4 * ACOLS * 16; idx += 256) {
    const int lr = idx / (ACOLS * 16);
    const int rem = idx - lr * (ACOLS * 16);
    const int col = rem >> 4;         // 0..57 (src col = col-1)
    const int ch = rem & 15;          // 16B chunk within 256B
    const int sr = rr0 + lr - 1;
    const int sc = col - 1;
    uint4 v;
    if ((unsigned)sr < 56u && (unsigned)sc < 56u) {
      v = *(const uint4*)(src + (((size_t)(b * 56 + sr) * 56 + sc) << 8) + (ch << 4));
    } else {
      v.x = v.y = v.z = v.w = 0u;
    }
    *(uint4*)(As + (lr * ACOLS + col) * ASTRIDE + (ch << 4)) = v;
  }
  __syncthreads();

  // ---- per-lane A base addresses for the 7 m-subtiles (tap offset is imm)
  int abase[7];
#pragma unroll
  for (int ms = 0; ms < 7; ++ms) {
    const int p = ms * 16 + lid;          // pixel in tile
    const int prow = (p >= 56) ? 1 : 0;
    const int cc = p - 56 * prow;
    abase[ms] = (prow * ACOLS + cc) * ASTRIDE + (grp << 4);
  }

  // ---- per-lane B address (step part is scalar-uniform, added per step)
  const int8_t* bptr = wT + (((size_t)(wbase + lid)) << 8) + (grp << 4);

  v4i acc[7][4];
#pragma unroll
  for (int i = 0; i < 7; ++i)
#pragma unroll
    for (int j = 0; j < 4; ++j) acc[i][j] = (v4i){0, 0, 0, 0};

  v4i bA[4], bB[4];
#pragma unroll
  for (int ns = 0; ns < 4; ++ns)
    bA[ns] = *(const v4i*)(bptr + (ns << 12));   // step 0: tap 0, icq 0

#pragma unroll
  for (int s = 0; s < NSTEP; ++s) {
    v4i* const cur = (s & 1) ? bB : bA;
    v4i* const nxt = (s & 1) ? bA : bB;
    if (s + 1 < NSTEP) {
      const int tap1 = (s + 1) >> 2, icq1 = (s + 1) & 3;
      const size_t soff = ((size_t)tap1 << 16) + (icq1 << 6);
#pragma unroll
      for (int ns = 0; ns < 4; ++ns)
        nxt[ns] = *(const v4i*)(bptr + soff + (ns << 12));
    }
    const int tap = s >> 2, icq = s & 3;
    const int ky = tap / 3, kx = tap % 3;
    const int OFF = (ky * ACOLS + kx) * ASTRIDE + (icq << 6);  // compile-time

    v4i af[7];
#pragma unroll
    for (int ms = 0; ms < 7; ++ms)
      af[ms] = *(const v4i*)(As + abase[ms] + OFF);

#pragma unroll
    for (int ms = 0; ms < 7; ++ms)
#pragma unroll
      for (int ns = 0; ns < 4; ++ns)
        acc[ms][ns] = __builtin_amdgcn_mfma_i32_16x16x64_i8(af[ms], cur[ns],
                                                            acc[ms][ns], 0, 0, 0);
  }

  // ---- epilogue (identical to verified R7) ----
  if (MODE == 0) {
#pragma unroll
    for (int ns = 0; ns < 4; ++ns) {
      const int oc = wbase + ns * 16 + lid;
      const float mu = mean[oc], rs = rsqrtf(var[oc] + BN_EPS), be = beta[oc];
#pragma unroll
      for (int ms = 0; ms < 7; ++ms)
#pragma unroll
        for (int q = 0; q < 4; ++q) {
          float bnv = ((float)acc[ms][ns][q] - mu) * rs + be;
          hs[(size_t)(m0 + ms * 16 + grp * 4 + q) * 256 + oc] =
              bnv >= 0.f ? (int8_t)1 : (int8_t)-1;
        }
    }
  } else {
#pragma unroll
    for (int ns = 0; ns < 4; ++ns) {
      const int oc = wbase + ns * 16 + lid;
      const float mu = mean[oc], rs = rsqrtf(var[oc] + BN_EPS), be = beta[oc];
      int hm[7][2], sx[7][2];
#pragma unroll
      for (int ms = 0; ms < 7; ++ms) {
        hm[ms][0] = imax(acc[ms][ns][0], acc[ms][ns][1]);
        hm[ms][1] = imax(acc[ms][ns][2], acc[ms][ns][3]);
      }
#pragma unroll
      for (int ms = 3; ms < 7; ++ms) {
        sx[ms][0] = __shfl_xor(hm[ms][0], 32);
        sx[ms][1] = __shfl_xor(hm[ms][1], 32);
      }
      float* const obase = outp + ((size_t)(b * 28 + rp) * 28) * 256 + oc;
#pragma unroll
      for (int ms = 0; ms < 4; ++ms)
#pragma unroll
        for (int q2 = 0; q2 < 2; ++q2) {
          int part; bool top;
          if (ms < 3) {
            top = true;
            part = (grp < 2) ? sx[ms + 3][q2] : sx[ms + 4][q2];
          } else {
            top = (grp < 2);
            part = sx[6][q2];
          }
          if (top) {
            const int m = ms * 16 + grp * 4 + 2 * q2;  // even, < 56
            const int mx = imax(hm[ms][q2], part);
            obase[(size_t)(m >> 1) * 256] = ((float)mx - mu) * rs + be;
          }
        }
    }
  }
}

// ---------------------------------------------------------------------------
extern "C" void kernel_launch(void* const* d_in, const int* in_sizes, int n_in,
                              void* d_out, int out_size, void* d_ws, size_t ws_size,
                              hipStream_t stream) {
  const float* x     = (const float*)d_in[0];
  const float* w1    = (const float*)d_in[1];
  const float* beta1 = (const float*)d_in[2];
  const float* mean1 = (const float*)d_in[3];
  const float* var1  = (const float*)d_in[4];
  const float* w2    = (const float*)d_in[5];
  const float* beta2 = (const float*)d_in[6];
  const float* mean2 = (const float*)d_in[7];
  const float* var2  = (const float*)d_in[8];
  float* out = (float*)d_out;

  const size_t NPIX = (size_t)Bn * H * Wd * C;  // 25690112
  int8_t* xs  = (int8_t*)d_ws;
  int8_t* hs  = xs + NPIX;
  int8_t* w1t = hs + NPIX;
  int8_t* w2t = w1t + 9 * 256 * 256;

  k_sign_x<<<dim3((int)(NPIX / 4 / 256)), 256, 0, stream>>>(x, xs, (int)(NPIX / 4));
  k_sign_wT<<<dim3(576), 256, 0, stream>>>(w1, w1t);
  k_sign_wT<<<dim3(576), 256, 0, stream>>>(w2, w2t);
  k_conv<0><<<dim3(28, Bn), 256, 0, stream>>>(xs, w1t, beta1, mean1, var1, hs, nullptr);
  k_conv<1><<<dim3(28, Bn), 256, 0, stream>>>(hs, w2t, beta2, mean2, var2, nullptr, out);
}

// Round 9
// 195.648 us; speedup vs baseline: 1.9727x; 1.0133x over previous
//
#include <hip/hip_runtime.h>
#include <stdint.h>

#define BN_EPS 1e-3f

constexpr int Bn = 32, H = 56, Wd = 56, C = 256;
constexpr int HO = 28, WO = 28;
constexpr int NSTEP = 36;            // K = 2304 = 36 * 64
constexpr int MT = 112;              // pixels per block = 2 image rows
constexpr int ACOLS = 58;            // 56 + 2 halo cols
// chunk-major LDS: byte addr = ((c*4 + row)*ACOLS + col)*16, c=0..15
constexpr int CPLANE = 4 * ACOLS * 16;   // 3712 bytes per chunk plane
constexpr int ASZ = 16 * CPLANE;         // 59392 bytes

typedef int v4i __attribute__((ext_vector_type(4)));

__device__ __forceinline__ int imax(int a, int b) { return a > b ? a : b; }

// ---------------------------------------------------------------------------
__global__ __launch_bounds__(256) void k_sign_x(const float* __restrict__ x,
                                                int8_t* __restrict__ xs, int n4) {
  int i = blockIdx.x * 256 + threadIdx.x;
  if (i >= n4) return;
  float4 v = ((const float4*)x)[i];
  char4 s;
  s.x = v.x >= 0.f ? 1 : -1;
  s.y = v.y >= 0.f ? 1 : -1;
  s.z = v.z >= 0.f ? 1 : -1;
  s.w = v.w >= 0.f ? 1 : -1;
  ((char4*)xs)[i] = s;
}

// ---------------------------------------------------------------------------
// Weights HWIO [9 tap][256 ic][256 oc] f32 -> wT[tap][oc][ic] i8 (sign).
__global__ __launch_bounds__(256) void k_sign_wT(const float* __restrict__ w,
                                                 int8_t* __restrict__ wt) {
  int u = blockIdx.x * 256 + threadIdx.x;       // 0 .. 147455
  int tap = u >> 14;
  int rem = u & 16383;
  int oc = rem >> 6;
  int icq = rem & 63;
  uint32_t pk = 0;
#pragma unroll
  for (int j = 0; j < 4; ++j) {
    float v = w[((size_t)(tap * 256 + icq * 4 + j)) * 256 + oc];
    uint32_t b = (v >= 0.f) ? 0x01u : 0xFFu;
    pk |= b << (8 * j);
  }
  ((uint32_t*)wt)[u] = pk;
}

// ---------------------------------------------------------------------------
// Implicit-GEMM conv, 3x3 SAME. A staged in LDS once (chunk-major, lane-
// consecutive 16B slots); K-loop barrier-free, 2-stage software pipeline:
// prefetch (7 ds_read + 4 global) for s+1, then 28 MFMA for s under setprio.
template <int MODE>
__global__ __launch_bounds__(256, 2) void k_conv(
    const int8_t* __restrict__ src, const int8_t* __restrict__ wT,
    const float* __restrict__ beta, const float* __restrict__ mean,
    const float* __restrict__ var,
    int8_t* __restrict__ hs, float* __restrict__ outp)
{
  const int t = threadIdx.x;
  const int lane = t & 63;
  const int wv = t >> 6;
  const int rp = blockIdx.x;
  const int b = blockIdx.y;
  const int rr0 = rp * 2;
  const int m0 = (b * 28 + rp) * MT;
  const int grp = lane >> 4, lid = lane & 15;
  const int wbase = wv * 64;

  __shared__ __align__(16) int8_t As[ASZ];

  // ---- stage A once: (row 0..3, col 0..57, chunk 0..15); coalesced global.
  for (int idx = t; idx < 4 * ACOLS * 16; idx += 256) {
    const int c = idx & 15;          // consecutive t -> consecutive 16B chunk
    const int rc = idx >> 4;
    const int col = rc % ACOLS;
    const int lr = rc / ACOLS;
    const int sr = rr0 + lr - 1;
    const int sc = col - 1;
    uint4 v;
    if ((unsigned)sr < 56u && (unsigned)sc < 56u) {
      v = *(const uint4*)(src + (((size_t)(b * 56 + sr) * 56 + sc) << 8) + (c << 4));
    } else {
      v.x = v.y = v.z = v.w = 0u;
    }
    *(uint4*)(As + c * CPLANE + (lr * ACOLS + col) * 16) = v;
  }
  __syncthreads();

  // ---- per-lane A bases: abase[ms] = grp*CPLANE + (prow*58+cc)*16
  int abase[7];
#pragma unroll
  for (int ms = 0; ms < 7; ++ms) {
    const int p = ms * 16 + lid;
    const int prow = (p >= 56) ? 1 : 0;
    const int cc = p - 56 * prow;
    abase[ms] = grp * CPLANE + (prow * ACOLS + cc) * 16;
  }

  const int8_t* bptr = wT + (((size_t)(wbase + lid)) << 8) + (grp << 4);

  v4i acc[7][4];
#pragma unroll
  for (int i = 0; i < 7; ++i)
#pragma unroll
    for (int j = 0; j < 4; ++j) acc[i][j] = (v4i){0, 0, 0, 0};

  v4i afA[7], afB[7], bA[4], bB[4];

#define LOADA(dst, s)                                                      \
  {                                                                        \
    constexpr int tap_ = (s) >> 2, icq_ = (s) & 3;                         \
    constexpr int ky_ = tap_ / 3, kx_ = tap_ % 3;                          \
    constexpr int OFF_ = icq_ * 4 * CPLANE + (ky_ * ACOLS + kx_) * 16;     \
    _Pragma("unroll") for (int ms = 0; ms < 7; ++ms)                       \
        dst[ms] = *(const v4i*)(As + abase[ms] + OFF_);                    \
  }

#define LOADB(dst, s)                                                      \
  {                                                                        \
    constexpr int tap_ = (s) >> 2, icq_ = (s) & 3;                         \
    constexpr size_t SOFF_ = ((size_t)tap_ << 16) + (icq_ << 6);           \
    _Pragma("unroll") for (int ns = 0; ns < 4; ++ns)                       \
        dst[ns] = *(const v4i*)(bptr + SOFF_ + (ns << 12));                \
  }

#define MFMA28(af, bf)                                                     \
  __builtin_amdgcn_s_setprio(1);                                           \
  _Pragma("unroll") for (int ms = 0; ms < 7; ++ms)                         \
  _Pragma("unroll") for (int ns = 0; ns < 4; ++ns)                         \
      acc[ms][ns] = __builtin_amdgcn_mfma_i32_16x16x64_i8(af[ms], bf[ns],  \
                                                          acc[ms][ns], 0, 0, 0); \
  __builtin_amdgcn_s_setprio(0);

  LOADB(bA, 0)
  LOADA(afA, 0)

#define STEP_PAIR(s0)                                                      \
  {                                                                        \
    LOADA(afB, (s0) + 1)                                                   \
    LOADB(bB, (s0) + 1)                                                    \
    MFMA28(afA, bA)                                                        \
    if constexpr ((s0) + 2 < NSTEP) {                                      \
      LOADA(afA, ((s0) + 2 < NSTEP) ? (s0) + 2 : 0)                        \
      LOADB(bA, ((s0) + 2 < NSTEP) ? (s0) + 2 : 0)                         \
    }                                                                      \
    MFMA28(afB, bB)                                                        \
  }

  STEP_PAIR(0)  STEP_PAIR(2)  STEP_PAIR(4)  STEP_PAIR(6)
  STEP_PAIR(8)  STEP_PAIR(10) STEP_PAIR(12) STEP_PAIR(14)
  STEP_PAIR(16) STEP_PAIR(18) STEP_PAIR(20) STEP_PAIR(22)
  STEP_PAIR(24) STEP_PAIR(26) STEP_PAIR(28) STEP_PAIR(30)
  STEP_PAIR(32) STEP_PAIR(34)

#undef STEP_PAIR
#undef MFMA28
#undef LOADB
#undef LOADA

  // ---- epilogue (verified in R7/R8) ----
  if (MODE == 0) {
#pragma unroll
    for (int ns = 0; ns < 4; ++ns) {
      const int oc = wbase + ns * 16 + lid;
      const float mu = mean[oc], rs = rsqrtf(var[oc] + BN_EPS), be = beta[oc];
#pragma unroll
      for (int ms = 0; ms < 7; ++ms)
#pragma unroll
        for (int q = 0; q < 4; ++q) {
          float bnv = ((float)acc[ms][ns][q] - mu) * rs + be;
          hs[(size_t)(m0 + ms * 16 + grp * 4 + q) * 256 + oc] =
              bnv >= 0.f ? (int8_t)1 : (int8_t)-1;
        }
    }
  } else {
#pragma unroll
    for (int ns = 0; ns < 4; ++ns) {
      const int oc = wbase + ns * 16 + lid;
      const float mu = mean[oc], rs = rsqrtf(var[oc] + BN_EPS), be = beta[oc];
      int hm[7][2], sx[7][2];
#pragma unroll
      for (int ms = 0; ms < 7; ++ms) {
        hm[ms][0] = imax(acc[ms][ns][0], acc[ms][ns][1]);
        hm[ms][1] = imax(acc[ms][ns][2], acc[ms][ns][3]);
      }
#pragma unroll
      for (int ms = 3; ms < 7; ++ms) {
        sx[ms][0] = __shfl_xor(hm[ms][0], 32);
        sx[ms][1] = __shfl_xor(hm[ms][1], 32);
      }
      float* const obase = outp + ((size_t)(b * 28 + rp) * 28) * 256 + oc;
#pragma unroll
      for (int ms = 0; ms < 4; ++ms)
#pragma unroll
        for (int q2 = 0; q2 < 2; ++q2) {
          int part; bool top;
          if (ms < 3) {
            top = true;
            part = (grp < 2) ? sx[ms + 3][q2] : sx[ms + 4][q2];
          } else {
            top = (grp < 2);
            part = sx[6][q2];
          }
          if (top) {
            const int m = ms * 16 + grp * 4 + 2 * q2;  // even, < 56
            const int mx = imax(hm[ms][q2], part);
            obase[(size_t)(m >> 1) * 256] = ((float)mx - mu) * rs + be;
          }
        }
    }
  }
}

// ---------------------------------------------------------------------------
extern "C" void kernel_launch(void* const* d_in, const int* in_sizes, int n_in,
                              void* d_out, int out_size, void* d_ws, size_t ws_size,
                              hipStream_t stream) {
  const float* x     = (const float*)d_in[0];
  const float* w1    = (const float*)d_in[1];
  const float* beta1 = (const float*)d_in[2];
  const float* mean1 = (const float*)d_in[3];
  const float* var1  = (const float*)d_in[4];
  const float* w2    = (const float*)d_in[5];
  const float* beta2 = (const float*)d_in[6];
  const float* mean2 = (const float*)d_in[7];
  const float* var2  = (const float*)d_in[8];
  float* out = (float*)d_out;

  const size_t NPIX = (size_t)Bn * H * Wd * C;  // 25690112
  int8_t* xs  = (int8_t*)d_ws;
  int8_t* hs  = xs + NPIX;
  int8_t* w1t = hs + NPIX;
  int8_t* w2t = w1t + 9 * 256 * 256;

  k_sign_x<<<dim3((int)(NPIX / 4 / 256)), 256, 0, stream>>>(x, xs, (int)(NPIX / 4));
  k_sign_wT<<<dim3(576), 256, 0, stream>>>(w1, w1t);
  k_sign_wT<<<dim3(576), 256, 0, stream>>>(w2, w2t);
  k_conv<0><<<dim3(28, Bn), 256, 0, stream>>>(xs, w1t, beta1, mean1, var1, hs, nullptr);
  k_conv<1><<<dim3(28, Bn), 256, 0, stream>>>(hs, w2t, beta2, mean2, var2, nullptr, out);
}

// Round 10
// 193.326 us; speedup vs baseline: 1.9964x; 1.0120x over previous
//
#include <hip/hip_runtime.h>
#include <stdint.h>

#define BN_EPS 1e-3f

constexpr int Bn = 32, H = 56, Wd = 56, C = 256;
constexpr int HO = 28, WO = 28;
constexpr int NSTEP = 36;            // K = 2304 = 36 * 64
constexpr int MT = 112;              // pixels per block = 2 image rows
constexpr int ACOLS = 58;            // 56 + 2 halo cols
// chunk-major LDS: byte addr = ((c*4 + row)*ACOLS + col)*16, c=0..15
constexpr int CPLANE = 4 * ACOLS * 16;   // 3712 bytes per chunk plane
constexpr int ASZ = 16 * CPLANE;         // 59392 bytes

typedef int v4i __attribute__((ext_vector_type(4)));

__device__ __forceinline__ int imax(int a, int b) { return a > b ? a : b; }

// ---------------------------------------------------------------------------
__global__ __launch_bounds__(256) void k_sign_x(const float* __restrict__ x,
                                                int8_t* __restrict__ xs, int n4) {
  int i = blockIdx.x * 256 + threadIdx.x;
  if (i >= n4) return;
  float4 v = ((const float4*)x)[i];
  char4 s;
  s.x = v.x >= 0.f ? 1 : -1;
  s.y = v.y >= 0.f ? 1 : -1;
  s.z = v.z >= 0.f ? 1 : -1;
  s.w = v.w >= 0.f ? 1 : -1;
  ((char4*)xs)[i] = s;
}

// ---------------------------------------------------------------------------
// Weights HWIO [9 tap][256 ic][256 oc] f32 -> wT[tap][oc][ic] i8 (sign).
__global__ __launch_bounds__(256) void k_sign_wT(const float* __restrict__ w,
                                                 int8_t* __restrict__ wt) {
  int u = blockIdx.x * 256 + threadIdx.x;       // 0 .. 147455
  int tap = u >> 14;
  int rem = u & 16383;
  int oc = rem >> 6;
  int icq = rem & 63;
  uint32_t pk = 0;
#pragma unroll
  for (int j = 0; j < 4; ++j) {
    float v = w[((size_t)(tap * 256 + icq * 4 + j)) * 256 + oc];
    uint32_t b = (v >= 0.f) ? 0x01u : 0xFFu;
    pk |= b << (8 * j);
  }
  ((uint32_t*)wt)[u] = pk;
}

// ---------------------------------------------------------------------------
// Implicit-GEMM conv, 3x3 SAME. 8 waves/block, each wave N=32 (2 n-subtiles),
// M=112 shared A in LDS (staged once). Small per-wave state (acc=56 VGPR)
// + __launch_bounds__(512,4) -> 4 waves/SIMD for latency hiding via TLP.
template <int MODE>
__global__ __launch_bounds__(512, 4) void k_conv(
    const int8_t* __restrict__ src, const int8_t* __restrict__ wT,
    const float* __restrict__ beta, const float* __restrict__ mean,
    const float* __restrict__ var,
    int8_t* __restrict__ hs, float* __restrict__ outp)
{
  const int t = threadIdx.x;
  const int lane = t & 63;
  const int wv = t >> 6;              // 0..7 -> oc 32-slice
  const int rp = blockIdx.x;
  const int b = blockIdx.y;
  const int rr0 = rp * 2;
  const int m0 = (b * 28 + rp) * MT;
  const int grp = lane >> 4, lid = lane & 15;
  const int wbase = wv * 32;

  __shared__ __align__(16) int8_t As[ASZ];

  // ---- per-lane A bases (before barrier, overlaps staging)
  int abase[7];
#pragma unroll
  for (int ms = 0; ms < 7; ++ms) {
    const int p = ms * 16 + lid;
    const int prow = (p >= 56) ? 1 : 0;
    const int cc = p - 56 * prow;
    abase[ms] = grp * CPLANE + (prow * ACOLS + cc) * 16;
  }

  // ---- stage A once (c-minor: coalesced global reads)
  for (int idx = t; idx < 4 * ACOLS * 16; idx += 512) {
    const int c = idx & 15;
    const int rc = idx >> 4;
    const int col = rc % ACOLS;
    const int lr = rc / ACOLS;
    const int sr = rr0 + lr - 1;
    const int sc = col - 1;
    uint4 v;
    if ((unsigned)sr < 56u && (unsigned)sc < 56u) {
      v = *(const uint4*)(src + (((size_t)(b * 56 + sr) * 56 + sc) << 8) + (c << 4));
    } else {
      v.x = v.y = v.z = v.w = 0u;
    }
    *(uint4*)(As + c * CPLANE + (lr * ACOLS + col) * 16) = v;
  }
  __syncthreads();

  const int8_t* bptr = wT + (((size_t)(wbase + lid)) << 8) + (grp << 4);

  v4i acc[7][2];
#pragma unroll
  for (int i = 0; i < 7; ++i)
#pragma unroll
    for (int j = 0; j < 2; ++j) acc[i][j] = (v4i){0, 0, 0, 0};

#pragma unroll
  for (int s = 0; s < NSTEP; ++s) {
    const int tap = s >> 2, icq = s & 3;
    const int ky = tap / 3, kx = tap % 3;
    const int OFF = icq * 4 * CPLANE + (ky * ACOLS + kx) * 16;  // folds to imm
    const size_t SOFF = ((size_t)tap << 16) + (icq << 6);

    v4i bf[2];
#pragma unroll
    for (int ns = 0; ns < 2; ++ns)
      bf[ns] = *(const v4i*)(bptr + SOFF + (ns << 12));

    v4i af[7];
#pragma unroll
    for (int ms = 0; ms < 7; ++ms)
      af[ms] = *(const v4i*)(As + abase[ms] + OFF);

    __builtin_amdgcn_s_setprio(1);
#pragma unroll
    for (int ms = 0; ms < 7; ++ms)
#pragma unroll
      for (int ns = 0; ns < 2; ++ns)
        acc[ms][ns] = __builtin_amdgcn_mfma_i32_16x16x64_i8(af[ms], bf[ns],
                                                            acc[ms][ns], 0, 0, 0);
    __builtin_amdgcn_s_setprio(0);
  }

  // ---- epilogue ----
  if (MODE == 0) {
#pragma unroll
    for (int ns = 0; ns < 2; ++ns) {
      const int oc = wbase + ns * 16 + lid;
      const float mu = mean[oc], rs = rsqrtf(var[oc] + BN_EPS), be = beta[oc];
#pragma unroll
      for (int ms = 0; ms < 7; ++ms)
#pragma unroll
        for (int q = 0; q < 4; ++q) {
          float bnv = ((float)acc[ms][ns][q] - mu) * rs + be;
          hs[(size_t)(m0 + ms * 16 + grp * 4 + q) * 256 + oc] =
              bnv >= 0.f ? (int8_t)1 : (int8_t)-1;
        }
    }
  } else {
#pragma unroll
    for (int ns = 0; ns < 2; ++ns) {
      const int oc = wbase + ns * 16 + lid;
      const float mu = mean[oc], rs = rsqrtf(var[oc] + BN_EPS), be = beta[oc];
      int hm[7][2], sx[7][2];
#pragma unroll
      for (int ms = 0; ms < 7; ++ms) {
        hm[ms][0] = imax(acc[ms][ns][0], acc[ms][ns][1]);
        hm[ms][1] = imax(acc[ms][ns][2], acc[ms][ns][3]);
      }
#pragma unroll
      for (int ms = 3; ms < 7; ++ms) {
        sx[ms][0] = __shfl_xor(hm[ms][0], 32);
        sx[ms][1] = __shfl_xor(hm[ms][1], 32);
      }
      float* const obase = outp + ((size_t)(b * 28 + rp) * 28) * 256 + oc;
#pragma unroll
      for (int ms = 0; ms < 4; ++ms)
#pragma unroll
        for (int q2 = 0; q2 < 2; ++q2) {
          int part; bool top;
          if (ms < 3) {
            top = true;
            part = (grp < 2) ? sx[ms + 3][q2] : sx[ms + 4][q2];
          } else {
            top = (grp < 2);
            part = sx[6][q2];
          }
          if (top) {
            const int m = ms * 16 + grp * 4 + 2 * q2;  // even, < 56
            const int mx = imax(hm[ms][q2], part);
            obase[(size_t)(m >> 1) * 256] = ((float)mx - mu) * rs + be;
          }
        }
    }
  }
}

// ---------------------------------------------------------------------------
extern "C" void kernel_launch(void* const* d_in, const int* in_sizes, int n_in,
                              void* d_out, int out_size, void* d_ws, size_t ws_size,
                              hipStream_t stream) {
  const float* x     = (const float*)d_in[0];
  const float* w1    = (const float*)d_in[1];
  const float* beta1 = (const float*)d_in[2];
  const float* mean1 = (const float*)d_in[3];
  const float* var1  = (const float*)d_in[4];
  const float* w2    = (const float*)d_in[5];
  const float* beta2 = (const float*)d_in[6];
  const float* mean2 = (const float*)d_in[7];
  const float* var2  = (const float*)d_in[8];
  float* out = (float*)d_out;

  const size_t NPIX = (size_t)Bn * H * Wd * C;  // 25690112
  int8_t* xs  = (int8_t*)d_ws;
  int8_t* hs  = xs + NPIX;
  int8_t* w1t = hs + NPIX;
  int8_t* w2t = w1t + 9 * 256 * 256;

  k_sign_x<<<dim3((int)(NPIX / 4 / 256)), 256, 0, stream>>>(x, xs, (int)(NPIX / 4));
  k_sign_wT<<<dim3(576), 256, 0, stream>>>(w1, w1t);
  k_sign_wT<<<dim3(576), 256, 0, stream>>>(w2, w2t);
  k_conv<0><<<dim3(28, Bn), 512, 0, stream>>>(xs, w1t, beta1, mean1, var1, hs, nullptr);
  k_conv<1><<<dim3(28, Bn), 512, 0, stream>>>(hs, w2t, beta2, mean2, var2, nullptr, out);
}

// Round 11
// 187.524 us; speedup vs baseline: 2.0582x; 1.0309x over previous
//
#include <hip/hip_runtime.h>
#include <stdint.h>

#define BN_EPS 1e-3f

constexpr int Bn = 32, H = 56, Wd = 56, C = 256;
constexpr int HO = 28, WO = 28;
constexpr int NSTEP = 36;            // K = 2304 = 36 * 64
constexpr int MT = 112;              // pixels per block = 2 image rows
constexpr int ACOLS = 58;            // 56 + 2 halo cols
// chunk-major LDS: byte addr = c*CPLANE + (row*ACOLS + col)*16, c=0..15
constexpr int CPLANE = 4 * ACOLS * 16;   // 3712 bytes per chunk plane
constexpr int ASZ = 16 * CPLANE;         // 59392 bytes

typedef int v4i __attribute__((ext_vector_type(4)));

__device__ __forceinline__ int imax(int a, int b) { return a > b ? a : b; }

// ---------------------------------------------------------------------------
__global__ __launch_bounds__(256) void k_sign_x(const float* __restrict__ x,
                                                int8_t* __restrict__ xs, int n4) {
  int i = blockIdx.x * 256 + threadIdx.x;
  if (i >= n4) return;
  float4 v = ((const float4*)x)[i];
  char4 s;
  s.x = v.x >= 0.f ? 1 : -1;
  s.y = v.y >= 0.f ? 1 : -1;
  s.z = v.z >= 0.f ? 1 : -1;
  s.w = v.w >= 0.f ? 1 : -1;
  ((char4*)xs)[i] = s;
}

// ---------------------------------------------------------------------------
// Weights HWIO [9 tap][256 ic][256 oc] f32 -> wT[tap][oc][ic] i8 (sign).
__global__ __launch_bounds__(256) void k_sign_wT(const float* __restrict__ w,
                                                 int8_t* __restrict__ wt) {
  int u = blockIdx.x * 256 + threadIdx.x;       // 0 .. 147455
  int tap = u >> 14;
  int rem = u & 16383;
  int oc = rem >> 6;
  int icq = rem & 63;
  uint32_t pk = 0;
#pragma unroll
  for (int j = 0; j < 4; ++j) {
    float v = w[((size_t)(tap * 256 + icq * 4 + j)) * 256 + oc];
    uint32_t b = (v >= 0.f) ? 0x01u : 0xFFu;
    pk |= b << (8 * j);
  }
  ((uint32_t*)wt)[u] = pk;
}

// ---------------------------------------------------------------------------
// Implicit-GEMM conv, 3x3 SAME. 8 waves/block, wave = 32-oc slice, M=112
// shared A in LDS (staged once). K-loop barrier-free with PER-WAVE STAGGERED
// K-START: wave wv begins at step (wv*9)>>1 and wraps mod 36 (integer sum is
// order-independent). Breaks inter-wave phase lock so one wave's MFMA covers
// another's load latency. B prefetched one step ahead (reg double-buffer).
template <int MODE>
__global__ __launch_bounds__(512, 4) void k_conv(
    const int8_t* __restrict__ src, const int8_t* __restrict__ wT,
    const float* __restrict__ beta, const float* __restrict__ mean,
    const float* __restrict__ var,
    int8_t* __restrict__ hs, float* __restrict__ outp)
{
  const int t = threadIdx.x;
  const int lane = t & 63;
  const int wv = t >> 6;              // 0..7 -> oc 32-slice
  const int rp = blockIdx.x;
  const int b = blockIdx.y;
  const int rr0 = rp * 2;
  const int m0 = (b * 28 + rp) * MT;
  const int grp = lane >> 4, lid = lane & 15;
  const int wbase = wv * 32;

  __shared__ __align__(16) int8_t As[ASZ];

  // ---- per-lane A bases
  int abase[7];
#pragma unroll
  for (int ms = 0; ms < 7; ++ms) {
    const int p = ms * 16 + lid;
    const int prow = (p >= 56) ? 1 : 0;
    const int cc = p - 56 * prow;
    abase[ms] = grp * CPLANE + (prow * ACOLS + cc) * 16;
  }

  // ---- stage A once (c-minor: coalesced global reads)
  for (int idx = t; idx < 4 * ACOLS * 16; idx += 512) {
    const int c = idx & 15;
    const int rc = idx >> 4;
    const int col = rc % ACOLS;
    const int lr = rc / ACOLS;
    const int sr = rr0 + lr - 1;
    const int sc = col - 1;
    uint4 v;
    if ((unsigned)sr < 56u && (unsigned)sc < 56u) {
      v = *(const uint4*)(src + (((size_t)(b * 56 + sr) * 56 + sc) << 8) + (c << 4));
    } else {
      v.x = v.y = v.z = v.w = 0u;
    }
    *(uint4*)(As + c * CPLANE + (lr * ACOLS + col) * 16) = v;
  }
  __syncthreads();

  const int8_t* bptr = wT + (((size_t)(wbase + lid)) << 8) + (grp << 4);

  // wave-uniform step -> byte offsets (forced scalar via readfirstlane)
  auto aoff = [&](int s) -> int {
    const int tap = s >> 2, icq = s & 3;
    const int ky = (tap >= 6) ? 2 : ((tap >= 3) ? 1 : 0);
    const int kx = tap - 3 * ky;
    return __builtin_amdgcn_readfirstlane(icq * (4 * CPLANE) +
                                          (ky * ACOLS + kx) * 16);
  };
  auto boff = [&](int s) -> int {
    const int tap = s >> 2, icq = s & 3;
    return __builtin_amdgcn_readfirstlane((tap << 16) + (icq << 6));
  };

  v4i acc[7][2];
#pragma unroll
  for (int i = 0; i < 7; ++i)
#pragma unroll
    for (int j = 0; j < 2; ++j) acc[i][j] = (v4i){0, 0, 0, 0};

#define LOADB(dst, o)                                                      \
  {                                                                        \
    const int8_t* p_ = bptr + (size_t)(uint32_t)(o);                       \
    _Pragma("unroll") for (int ns = 0; ns < 2; ++ns)                       \
        dst[ns] = *(const v4i*)(p_ + (ns << 12));                          \
  }

#define LOADA(o)                                                           \
  {                                                                        \
    const int o_ = (o);                                                    \
    _Pragma("unroll") for (int ms = 0; ms < 7; ++ms)                       \
        af[ms] = *(const v4i*)(As + abase[ms] + o_);                       \
  }

#define MFMA14(bf)                                                         \
  __builtin_amdgcn_s_setprio(1);                                           \
  _Pragma("unroll") for (int ms = 0; ms < 7; ++ms)                         \
  _Pragma("unroll") for (int ns = 0; ns < 2; ++ns)                         \
      acc[ms][ns] = __builtin_amdgcn_mfma_i32_16x16x64_i8(af[ms], bf[ns],  \
                                                          acc[ms][ns], 0, 0, 0); \
  __builtin_amdgcn_s_setprio(0);

  int s = (wv * 9) >> 1;              // stagger: 0,4,9,13,18,22,27,31
  v4i af[7], bfA[2], bfB[2];
  LOADB(bfA, boff(s))

#pragma unroll 1
  for (int i = 0; i < NSTEP; i += 2) {
    int s1 = s + 1; if (s1 >= NSTEP) s1 -= NSTEP;
    LOADB(bfB, boff(s1))              // prefetch next step's B
    LOADA(aoff(s))
    MFMA14(bfA)
    int s2 = s1 + 1; if (s2 >= NSTEP) s2 -= NSTEP;
    LOADB(bfA, boff(s2))
    LOADA(aoff(s1))
    MFMA14(bfB)
    s = s2;
  }

#undef MFMA14
#undef LOADA
#undef LOADB

  // ---- epilogue (verified R7-R10) ----
  if (MODE == 0) {
#pragma unroll
    for (int ns = 0; ns < 2; ++ns) {
      const int oc = wbase + ns * 16 + lid;
      const float mu = mean[oc], rs = rsqrtf(var[oc] + BN_EPS), be = beta[oc];
#pragma unroll
      for (int ms = 0; ms < 7; ++ms)
#pragma unroll
        for (int q = 0; q < 4; ++q) {
          float bnv = ((float)acc[ms][ns][q] - mu) * rs + be;
          hs[(size_t)(m0 + ms * 16 + grp * 4 + q) * 256 + oc] =
              bnv >= 0.f ? (int8_t)1 : (int8_t)-1;
        }
    }
  } else {
#pragma unroll
    for (int ns = 0; ns < 2; ++ns) {
      const int oc = wbase + ns * 16 + lid;
      const float mu = mean[oc], rs = rsqrtf(var[oc] + BN_EPS), be = beta[oc];
      int hm[7][2], sx[7][2];
#pragma unroll
      for (int ms = 0; ms < 7; ++ms) {
        hm[ms][0] = imax(acc[ms][ns][0], acc[ms][ns][1]);
        hm[ms][1] = imax(acc[ms][ns][2], acc[ms][ns][3]);
      }
#pragma unroll
      for (int ms = 3; ms < 7; ++ms) {
        sx[ms][0] = __shfl_xor(hm[ms][0], 32);
        sx[ms][1] = __shfl_xor(hm[ms][1], 32);
      }
      float* const obase = outp + ((size_t)(b * 28 + rp) * 28) * 256 + oc;
#pragma unroll
      for (int ms = 0; ms < 4; ++ms)
#pragma unroll
        for (int q2 = 0; q2 < 2; ++q2) {
          int part; bool top;
          if (ms < 3) {
            top = true;
            part = (grp < 2) ? sx[ms + 3][q2] : sx[ms + 4][q2];
          } else {
            top = (grp < 2);
            part = sx[6][q2];
          }
          if (top) {
            const int m = ms * 16 + grp * 4 + 2 * q2;  // even, < 56
            const int mx = imax(hm[ms][q2], part);
            obase[(size_t)(m >> 1) * 256] = ((float)mx - mu) * rs + be;
          }
        }
    }
  }
}

// ---------------------------------------------------------------------------
extern "C" void kernel_launch(void* const* d_in, const int* in_sizes, int n_in,
                              void* d_out, int out_size, void* d_ws, size_t ws_size,
                              hipStream_t stream) {
  const float* x     = (const float*)d_in[0];
  const float* w1    = (const float*)d_in[1];
  const float* beta1 = (const float*)d_in[2];
  const float* mean1 = (const float*)d_in[3];
  const float* var1  = (const float*)d_in[4];
  const float* w2    = (const float*)d_in[5];
  const float* beta2 = (const float*)d_in[6];
  const float* mean2 = (const float*)d_in[7];
  const float* var2  = (const float*)d_in[8];
  float* out = (float*)d_out;

  const size_t NPIX = (size_t)Bn * H * Wd * C;  // 25690112
  int8_t* xs  = (int8_t*)d_ws;
  int8_t* hs  = xs + NPIX;
  int8_t* w1t = hs + NPIX;
  int8_t* w2t = w1t + 9 * 256 * 256;

  k_sign_x<<<dim3((int)(NPIX / 4 / 256)), 256, 0, stream>>>(x, xs, (int)(NPIX / 4));
  k_sign_wT<<<dim3(576), 256, 0, stream>>>(w1, w1t);
  k_sign_wT<<<dim3(576), 256, 0, stream>>>(w2, w2t);
  k_conv<0><<<dim3(28, Bn), 512, 0, stream>>>(xs, w1t, beta1, mean1, var1, hs, nullptr);
  k_conv<1><<<dim3(28, Bn), 512, 0, stream>>>(hs, w2t, beta2, mean2, var2, nullptr, out);
}

// Round 12
// 150.532 us; speedup vs baseline: 2.5640x; 1.2457x over previous
//
#include <hip/hip_runtime.h>
#include <stdint.h>

#define BN_EPS 1e-3f

constexpr int Bn = 32, H = 56, Wd = 56, C = 256;
constexpr int NSLOT = 232;          // 4 staged input rows * 58 cols (w/ halo)
typedef int v4i __attribute__((ext_vector_type(4)));

__device__ __forceinline__ int imax(int a, int b) { return a > b ? a : b; }

// ---------------------------------------------------------------------------
// sign(x) -> i8 {+1,-1}
__global__ __launch_bounds__(256) void k_sign_x(const float* __restrict__ x,
                                                int8_t* __restrict__ xs, int n4) {
  int i = blockIdx.x * 256 + threadIdx.x;
  if (i >= n4) return;
  float4 v = ((const float4*)x)[i];
  char4 s;
  s.x = v.x >= 0.f ? 1 : -1;
  s.y = v.y >= 0.f ? 1 : -1;
  s.z = v.z >= 0.f ? 1 : -1;
  s.w = v.w >= 0.f ? 1 : -1;
  ((char4*)xs)[i] = s;
}

// ---------------------------------------------------------------------------
// Fragment-contiguous weights:
// wT2 bytes [f = (tap*4+icq)*16 + ocg][l = grp*16+lid][bb 0..15]
//   = sign(w[tap][ic = icq*64 + grp*16 + bb][oc = ocg*16 + lid])
// A wave's B-fragment (f) is a contiguous 1KB block, lane-minor 16B coalesced.
__global__ __launch_bounds__(256) void k_sign_wT2(const float* __restrict__ w,
                                                  uint32_t* __restrict__ wt) {
  int u = blockIdx.x * 256 + threadIdx.x;   // 0..147455
  int f = u >> 8, r = u & 255;
  int l = r >> 2, w4 = r & 3;
  int grp = l >> 4, lid = l & 15;
  int tap = f >> 6, icq = (f >> 4) & 3, ocg = f & 15;
  int oc = ocg * 16 + lid;
  uint32_t pk = 0;
#pragma unroll
  for (int j = 0; j < 4; ++j) {
    int ic = icq * 64 + grp * 16 + w4 * 4 + j;
    float v = w[((size_t)(tap * 256 + ic)) * 256 + oc];
    pk |= (v >= 0.f ? 0x01u : 0xFFu) << (8 * j);
  }
  wt[u] = pk;
}

// ---------------------------------------------------------------------------
// Per-wave GEMM body. Wave covers M-pixels [(MSB)*16, (MSB+MS)*16) x N=128.
// m-index is PERMUTED: pixel m -> (row = m&1, col = m>>1), so the 2x2 maxpool
// window == one lane's q-quad (lane-local, no shuffles).
// A in LDS, XOR-swizzled: byte(slot s, logical off o) = s*256 + (o ^ ((s&7)<<4)).
template <int MODE, int MS, int MSB>
__device__ __forceinline__ void conv_body(
    const int8_t* As, const int8_t* __restrict__ wT2, int wn, int lane,
    const float* __restrict__ beta, const float* __restrict__ mean,
    const float* __restrict__ var, int8_t* __restrict__ hs,
    float* __restrict__ outp, int b, int rp)
{
  const int grp = lane >> 4, lid = lane & 15;
  const int wbase = wn * 128;
  const int cstg = grp << 4;

  int sb[MS], sb7[MS];
#pragma unroll
  for (int ms = 0; ms < MS; ++ms) {
    const int m = (MSB + ms) * 16 + lid;
    sb[ms] = (m & 1) * 58 + (m >> 1);
    sb7[ms] = sb[ms] & 7;
  }

  const int8_t* bpl = wT2 + (size_t)wn * 8192 + (size_t)lane * 16;

  v4i acc[MS][8];
#pragma unroll
  for (int i = 0; i < MS; ++i)
#pragma unroll
    for (int j = 0; j < 8; ++j) acc[i][j] = (v4i){0, 0, 0, 0};

#pragma unroll 1
  for (int ky = 0; ky < 3; ++ky) {
#pragma unroll 1
    for (int kx = 0; kx < 3; ++kx) {
      const int D = ky * 58 + kx;
      const int8_t* bt = bpl + (size_t)(ky * 3 + kx) * 65536;
      int slin[MS], key[MS];
#pragma unroll
      for (int ms = 0; ms < MS; ++ms) {
        slin[ms] = (sb[ms] + D) << 8;
        key[ms] = ((sb7[ms] + D) & 7) << 4;
      }
#pragma unroll
      for (int icq = 0; icq < 4; ++icq) {
        v4i bf[8];
#pragma unroll
        for (int ns = 0; ns < 8; ++ns)
          bf[ns] = *(const v4i*)(bt + icq * 16384 + ns * 1024);
        v4i af[MS];
#pragma unroll
        for (int ms = 0; ms < MS; ++ms)
          af[ms] = *(const v4i*)(As + slin[ms] + ((cstg + icq * 64) ^ key[ms]));
        __builtin_amdgcn_s_setprio(1);
#pragma unroll
        for (int ms = 0; ms < MS; ++ms)
#pragma unroll
          for (int ns = 0; ns < 8; ++ns)
            acc[ms][ns] = __builtin_amdgcn_mfma_i32_16x16x64_i8(
                af[ms], bf[ns], acc[ms][ns], 0, 0, 0);
        __builtin_amdgcn_s_setprio(0);
      }
    }
  }

  const int rA = rp * 2;
  if (MODE == 0) {
    // BN1 + sign -> hs (standard NHWC i8)
#pragma unroll
    for (int ns = 0; ns < 8; ++ns) {
      const int oc = wbase + ns * 16 + lid;
      const float mu = mean[oc], rs = rsqrtf(var[oc] + BN_EPS), be = beta[oc];
#pragma unroll
      for (int ms = 0; ms < MS; ++ms)
#pragma unroll
        for (int q = 0; q < 4; ++q) {
          const int m = (MSB + ms) * 16 + grp * 4 + q;
          const int lr = m & 1, col = m >> 1;
          const float bnv = ((float)acc[ms][ns][q] - mu) * rs + be;
          hs[(((size_t)(b * 56 + rA + lr)) * 56 + col) * 256 + oc] =
              bnv >= 0.f ? (int8_t)1 : (int8_t)-1;
        }
    }
  } else {
    // maxpool (lane-local q-quad) + BN2 -> f32
#pragma unroll
    for (int ns = 0; ns < 8; ++ns) {
      const int oc = wbase + ns * 16 + lid;
      const float mu = mean[oc], rs = rsqrtf(var[oc] + BN_EPS), be = beta[oc];
#pragma unroll
      for (int ms = 0; ms < MS; ++ms) {
        const int mx = imax(imax(acc[ms][ns][0], acc[ms][ns][1]),
                            imax(acc[ms][ns][2], acc[ms][ns][3]));
        const int j = (MSB + ms) * 4 + grp;   // pooled col 0..27
        outp[(((size_t)(b * 28 + rp)) * 28 + j) * 256 + oc] =
            ((float)mx - mu) * rs + be;
      }
    }
  }
}

// ---------------------------------------------------------------------------
// 4 waves = 2 wm (M-halves: ms 0-3 / 4-6) x 2 wn (oc halves, N=128 each).
template <int MODE>
__global__ __launch_bounds__(256, 2) void k_conv(
    const int8_t* __restrict__ src, const int8_t* __restrict__ wT2,
    const float* __restrict__ beta, const float* __restrict__ mean,
    const float* __restrict__ var,
    int8_t* __restrict__ hs, float* __restrict__ outp)
{
  const int t = threadIdx.x;
  const int rp = blockIdx.x;          // row pair 0..27
  const int b = blockIdx.y;
  const int rr0 = rp * 2;

  __shared__ __align__(16) int8_t As[NSLOT * 256];   // 59392 B

  // Stage A once: slot s = lr*58+col (input rows rr0-1..rr0+2, halo cols),
  // chunk c = 16B of the 256-ic vector. Swizzled dest, conflict-free writes,
  // coalesced global reads.
  for (int i = t; i < NSLOT * 16; i += 256) {
    const int s = i >> 4, c = i & 15;
    const int lr = s / 58, colst = s - lr * 58;
    const int sr = rr0 + lr - 1, sc = colst - 1;
    uint4 v;
    v.x = v.y = v.z = v.w = 0u;
    if ((unsigned)sr < 56u && (unsigned)sc < 56u)
      v = *(const uint4*)(src + (((size_t)(b * 56 + sr)) * 56 + sc) * 256 + c * 16);
    *(uint4*)(As + (s << 8) + ((c << 4) ^ ((s & 7) << 4))) = v;
  }
  __syncthreads();

  const int lane = t & 63;
  const int wv = t >> 6;
  const int wm = wv >> 1, wn = wv & 1;
  if (wm == 0)
    conv_body<MODE, 4, 0>(As, wT2, wn, lane, beta, mean, var, hs, outp, b, rp);
  else
    conv_body<MODE, 3, 4>(As, wT2, wn, lane, beta, mean, var, hs, outp, b, rp);
}

// ---------------------------------------------------------------------------
extern "C" void kernel_launch(void* const* d_in, const int* in_sizes, int n_in,
                              void* d_out, int out_size, void* d_ws, size_t ws_size,
                              hipStream_t stream) {
  const float* x     = (const float*)d_in[0];
  const float* w1    = (const float*)d_in[1];
  const float* beta1 = (const float*)d_in[2];
  const float* mean1 = (const float*)d_in[3];
  const float* var1  = (const float*)d_in[4];
  const float* w2    = (const float*)d_in[5];
  const float* beta2 = (const float*)d_in[6];
  const float* mean2 = (const float*)d_in[7];
  const float* var2  = (const float*)d_in[8];
  float* out = (float*)d_out;

  const size_t NPIX = (size_t)Bn * H * Wd * C;  // 25690112
  int8_t* xs  = (int8_t*)d_ws;
  int8_t* hs  = xs + NPIX;
  int8_t* w1t = hs + NPIX;
  int8_t* w2t = w1t + 589824;

  k_sign_x<<<dim3((int)(NPIX / 4 / 256)), 256, 0, stream>>>(x, xs, (int)(NPIX / 4));
  k_sign_wT2<<<dim3(576), 256, 0, stream>>>(w1, (uint32_t*)w1t);
  k_sign_wT2<<<dim3(576), 256, 0, stream>>>(w2, (uint32_t*)w2t);
  k_conv<0><<<dim3(28, Bn), 256, 0, stream>>>(xs, w1t, beta1, mean1, var1, hs, nullptr);
  k_conv<1><<<dim3(28, Bn), 256, 0, stream>>>(hs, w2t, beta2, mean2, var2, nullptr, out);
}